// Round 7
// baseline (529.535 us; speedup 1.0000x reference)
//
#include <hip/hip_runtime.h>
#include <hip/hip_bf16.h>
#include <math.h>

// Problem constants (fixed by the reference):
#define N_  32
#define S_  4096
#define H_  16
#define E_  64
#define D_  64
#define HE  (H_ * E_)   // 1024 floats = 4 KiB per s-row (same for V since D_==E_)

typedef float f32x4 __attribute__((ext_vector_type(4)));

// Fused flash-decode with inline split-S reduction.
// Phase 1 (all live blocks): block = (chunk, n), 256 threads = 16 head-groups
// x 16 lanes. Per s the block reads the CONTIGUOUS 4 KiB row K[n,s,:,:] and
// V row (one float4/thread, non-temporal), software-pipelined one pair ahead.
// Partial (m, l, acc[64]) per (n,h,chunk) goes to d_ws.
// Phase 2 (last-arriving block per (n,h), via atomic counter): 16-lane group
// h online-merges all nv chunks in FIXED order 0..nv-1 (bit-deterministic)
// and writes out[n,h,:]. threadfence release/acquire handles cross-XCD L2.
__global__ __launch_bounds__(256, 6)
void attn_fused(const float* __restrict__ q,
                const float* __restrict__ k,
                const float* __restrict__ v,
                const int* __restrict__ lens,
                float* __restrict__ ws_m,
                float* __restrict__ ws_l,
                float* __restrict__ ws_acc,
                int* __restrict__ cnt,
                float* __restrict__ out,
                int chunk_sz, int nchunk)
{
    const int chunk = blockIdx.x;
    const int n     = blockIdx.y;

    const int len = lens[n];
    const int s0  = chunk * chunk_sz;
    if (s0 >= len) return;                        // dead chunk: no work, no writes
    const int s1  = min(s0 + chunk_sz, len);
    const int nv  = (len + chunk_sz - 1) / chunk_sz;   // live chunks for this n

    const int tid = threadIdx.x;
    const int h   = tid >> 4;                     // head 0..15
    const int t   = tid & 15;                     // dim quarter: e = 4t..4t+3

    f32x4 q4 = *(const f32x4*)(q + (size_t)(n * H_ + h) * E_ + 4 * t);
    q4 *= 0.125f;                                 // fold 1/sqrt(64) into q

    const size_t elem = (size_t)h * E_ + 4 * t;
    const float* kp = k + (size_t)n * S_ * HE + (size_t)s0 * HE + elem;
    const float* vp = v + (size_t)n * S_ * HE + (size_t)s0 * HE + elem;

    float m = -1e30f, l = 0.f;
    f32x4 acc = (f32x4)0.f;

    const int cnt_s = s1 - s0;
    const int npair = cnt_s >> 1;

    auto consume = [&](const f32x4& Ka, const f32x4& Kb,
                       const f32x4& Va, const f32x4& Vb) {
        float xa = Ka.x * q4.x + Ka.y * q4.y + Ka.z * q4.z + Ka.w * q4.w;
        float xb = Kb.x * q4.x + Kb.y * q4.y + Kb.z * q4.z + Kb.w * q4.w;
        xa += __shfl_xor(xa, 1, 64);  xb += __shfl_xor(xb, 1, 64);
        xa += __shfl_xor(xa, 2, 64);  xb += __shfl_xor(xb, 2, 64);
        xa += __shfl_xor(xa, 4, 64);  xb += __shfl_xor(xb, 4, 64);
        xa += __shfl_xor(xa, 8, 64);  xb += __shfl_xor(xb, 8, 64);

        const float mn = fmaxf(m, fmaxf(xa, xb));
        const float sc = __expf(m - mn);
        const float wa = __expf(xa - mn);
        const float wb = __expf(xb - mn);
        l = l * sc + wa + wb;
        acc.x = acc.x * sc + wa * Va.x + wb * Vb.x;
        acc.y = acc.y * sc + wa * Va.y + wb * Vb.y;
        acc.z = acc.z * sc + wa * Va.z + wb * Vb.z;
        acc.w = acc.w * sc + wa * Va.w + wb * Vb.w;
        m = mn;
    };

    if (npair > 0) {
        f32x4 ka = __builtin_nontemporal_load((const f32x4*)kp);
        f32x4 kb = __builtin_nontemporal_load((const f32x4*)(kp + HE));
        f32x4 va = __builtin_nontemporal_load((const f32x4*)vp);
        f32x4 vb = __builtin_nontemporal_load((const f32x4*)(vp + HE));
        kp += 2 * HE; vp += 2 * HE;

        for (int i = 1; i < npair; ++i) {
            const f32x4 ka2 = __builtin_nontemporal_load((const f32x4*)kp);
            const f32x4 kb2 = __builtin_nontemporal_load((const f32x4*)(kp + HE));
            const f32x4 va2 = __builtin_nontemporal_load((const f32x4*)vp);
            const f32x4 vb2 = __builtin_nontemporal_load((const f32x4*)(vp + HE));
            kp += 2 * HE; vp += 2 * HE;

            consume(ka, kb, va, vb);

            ka = ka2; kb = kb2; va = va2; vb = vb2;
        }
        consume(ka, kb, va, vb);
    }

    if (cnt_s & 1) {                              // block-uniform odd tail row
        const f32x4 ka = __builtin_nontemporal_load((const f32x4*)kp);
        const f32x4 va = __builtin_nontemporal_load((const f32x4*)vp);
        float xa = ka.x * q4.x + ka.y * q4.y + ka.z * q4.z + ka.w * q4.w;
        xa += __shfl_xor(xa, 1, 64);
        xa += __shfl_xor(xa, 2, 64);
        xa += __shfl_xor(xa, 4, 64);
        xa += __shfl_xor(xa, 8, 64);
        const float mn = fmaxf(m, xa);
        const float sc = __expf(m - mn);
        const float wa = __expf(xa - mn);
        l = l * sc + wa;
        acc.x = acc.x * sc + wa * va.x;
        acc.y = acc.y * sc + wa * va.y;
        acc.z = acc.z * sc + wa * va.z;
        acc.w = acc.w * sc + wa * va.w;
        m = mn;
    }

    // ---- write partial for (n, h, chunk) ----
    const int nh = n * H_ + h;
    const size_t pidx = (size_t)nh * nchunk + chunk;
    if (t == 0) { ws_m[pidx] = m; ws_l[pidx] = l; }
    *(f32x4*)(ws_acc + pidx * 64 + 4 * t) = acc;

    // ---- release: my stores visible agent-wide, then count this chunk ----
    __threadfence();
    __syncthreads();

    __shared__ char lastf[H_];
    if (t == 0) {
        const int old = atomicAdd(&cnt[nh], 1);   // device-scope (m20)
        lastf[h] = (old == nv - 1) ? 1 : 0;
    }
    __syncthreads();

    if (!lastf[h]) return;

    // ---- acquire: invalidate stale cached lines before reading partials ----
    __threadfence();

    // ---- merge head h: fixed order c = 0..nv-1 (deterministic) ----
    const size_t base = (size_t)nh * nchunk;
    float M = -1e30f, L = 0.f;
    f32x4 A = (f32x4)0.f;
    #pragma unroll 2
    for (int c = 0; c < nv; ++c) {
        const float mc = ws_m[base + c];          // broadcast within group
        const float lc = ws_l[base + c];
        const f32x4 ac = *(const f32x4*)(ws_acc + (base + c) * 64 + 4 * t);
        const float mn = fmaxf(M, mc);
        const float so = __expf(M - mn);
        const float sn = __expf(mc - mn);
        L = L * so + lc * sn;
        A.x = A.x * so + ac.x * sn;
        A.y = A.y * so + ac.y * sn;
        A.z = A.z * so + ac.z * sn;
        A.w = A.w * so + ac.w * sn;
        M = mn;
    }
    const float inv = 1.f / L;
    f32x4 O; O.x = A.x * inv; O.y = A.y * inv; O.z = A.z * inv; O.w = A.w * inv;
    *(f32x4*)(out + (size_t)nh * D_ + 4 * t) = O;
}

extern "C" void kernel_launch(void* const* d_in, const int* in_sizes, int n_in,
                              void* d_out, int out_size, void* d_ws, size_t ws_size,
                              hipStream_t stream) {
    const float* q    = (const float*)d_in[0];   // [N,H,E]
    const float* k    = (const float*)d_in[1];   // [N,S,H,E]
    const float* v    = (const float*)d_in[2];   // [N,S,H,D]
    const int*   lens = (const int*)d_in[3];     // [N]
    float* out = (float*)d_out;                  // [N,H,D]

    const size_t NH = (size_t)N_ * H_;
    // workspace: cnt[NH] | m[NH*nchunk] | l[NH*nchunk] | acc[NH*nchunk*64]
    int nchunk = 8;
    if      (ws_size >= (NH * 128 * 66 + NH) * sizeof(float)) nchunk = 128; // ~17.3 MB
    else if (ws_size >= (NH * 64  * 66 + NH) * sizeof(float)) nchunk = 64;
    else if (ws_size >= (NH * 32  * 66 + NH) * sizeof(float)) nchunk = 32;
    else if (ws_size >= (NH * 16  * 66 + NH) * sizeof(float)) nchunk = 16;
    const int chunk_sz = S_ / nchunk;

    int*   cnt    = (int*)d_ws;
    float* ws_m   = (float*)(cnt + NH);
    float* ws_l   = ws_m + NH * nchunk;
    float* ws_acc = ws_l + NH * nchunk;

    // zero the per-(n,h) chunk counters (2 KB) — graph-capture-safe async op
    hipMemsetAsync(cnt, 0, NH * sizeof(int), stream);

    dim3 g1(nchunk, N_);
    attn_fused<<<g1, 256, 0, stream>>>(q, k, v, lens, ws_m, ws_l, ws_acc,
                                       cnt, out, chunk_sz, nchunk);
}

// Round 8
// 97.339 us; speedup vs baseline: 5.4401x; 5.4401x over previous
//
#include <hip/hip_runtime.h>
#include <hip/hip_bf16.h>
#include <math.h>

// Problem constants (fixed by the reference):
#define N_  32
#define S_  4096
#define H_  16
#define E_  64
#define D_  64
#define HE  (H_ * E_)   // 1024 floats = 4 KiB per s-row (same for V since D_==E_)

typedef float f32x4 __attribute__((ext_vector_type(4)));

// NOTE (R7 lesson): do NOT fuse the reduce into kernel 1 with an atomic
// counter + __threadfence. Agent-scope fences on gfx950 force per-XCD L2
// writeback/invalidate per block (L2s are not cross-XCD coherent) -> 5.4x
// regression (98.5 -> 529 us measured). Two dispatches are the cheap global
// barrier.

// Kernel 1: block = (chunk, n). 256 threads = 16 head-groups x 16 lanes.
// Per s the block reads the CONTIGUOUS 4 KiB row K[n,s,:,:] and V row
// (one float4/thread, non-temporal). Software-pipelined one pair ahead.
__global__ __launch_bounds__(256, 6)
void attn_partial(const float* __restrict__ q,
                  const float* __restrict__ k,
                  const float* __restrict__ v,
                  const int* __restrict__ lens,
                  float* __restrict__ ws_m,
                  float* __restrict__ ws_l,
                  float* __restrict__ ws_acc,
                  int chunk_sz, int nchunk)
{
    const int chunk = blockIdx.x;
    const int n     = blockIdx.y;

    const int len = lens[n];
    const int s0  = chunk * chunk_sz;
    if (s0 >= len) return;                        // dead chunk: no work, no writes
    const int s1  = min(s0 + chunk_sz, len);

    const int tid = threadIdx.x;
    const int h   = tid >> 4;                     // head 0..15
    const int t   = tid & 15;                     // dim quarter: e = 4t..4t+3

    f32x4 q4 = *(const f32x4*)(q + (size_t)(n * H_ + h) * E_ + 4 * t);
    q4 *= 0.125f;                                 // fold 1/sqrt(64) into q

    const size_t elem = (size_t)h * E_ + 4 * t;
    const float* kp = k + (size_t)n * S_ * HE + (size_t)s0 * HE + elem;
    const float* vp = v + (size_t)n * S_ * HE + (size_t)s0 * HE + elem;

    float m = -1e30f, l = 0.f;
    f32x4 acc = (f32x4)0.f;

    const int cnt   = s1 - s0;
    const int npair = cnt >> 1;

    auto consume = [&](const f32x4& Ka, const f32x4& Kb,
                       const f32x4& Va, const f32x4& Vb) {
        float xa = Ka.x * q4.x + Ka.y * q4.y + Ka.z * q4.z + Ka.w * q4.w;
        float xb = Kb.x * q4.x + Kb.y * q4.y + Kb.z * q4.z + Kb.w * q4.w;
        xa += __shfl_xor(xa, 1, 64);  xb += __shfl_xor(xb, 1, 64);
        xa += __shfl_xor(xa, 2, 64);  xb += __shfl_xor(xb, 2, 64);
        xa += __shfl_xor(xa, 4, 64);  xb += __shfl_xor(xb, 4, 64);
        xa += __shfl_xor(xa, 8, 64);  xb += __shfl_xor(xb, 8, 64);

        const float mn = fmaxf(m, fmaxf(xa, xb));
        const float sc = __expf(m - mn);
        const float wa = __expf(xa - mn);
        const float wb = __expf(xb - mn);
        l = l * sc + wa + wb;
        acc.x = acc.x * sc + wa * Va.x + wb * Vb.x;
        acc.y = acc.y * sc + wa * Va.y + wb * Vb.y;
        acc.z = acc.z * sc + wa * Va.z + wb * Vb.z;
        acc.w = acc.w * sc + wa * Va.w + wb * Vb.w;
        m = mn;
    };

    if (npair > 0) {
        f32x4 ka = __builtin_nontemporal_load((const f32x4*)kp);
        f32x4 kb = __builtin_nontemporal_load((const f32x4*)(kp + HE));
        f32x4 va = __builtin_nontemporal_load((const f32x4*)vp);
        f32x4 vb = __builtin_nontemporal_load((const f32x4*)(vp + HE));
        kp += 2 * HE; vp += 2 * HE;

        for (int i = 1; i < npair; ++i) {
            const f32x4 ka2 = __builtin_nontemporal_load((const f32x4*)kp);
            const f32x4 kb2 = __builtin_nontemporal_load((const f32x4*)(kp + HE));
            const f32x4 va2 = __builtin_nontemporal_load((const f32x4*)vp);
            const f32x4 vb2 = __builtin_nontemporal_load((const f32x4*)(vp + HE));
            kp += 2 * HE; vp += 2 * HE;

            consume(ka, kb, va, vb);

            ka = ka2; kb = kb2; va = va2; vb = vb2;
        }
        consume(ka, kb, va, vb);
    }

    if (cnt & 1) {                                // block-uniform odd tail row
        const f32x4 ka = __builtin_nontemporal_load((const f32x4*)kp);
        const f32x4 va = __builtin_nontemporal_load((const f32x4*)vp);
        float xa = ka.x * q4.x + ka.y * q4.y + ka.z * q4.z + ka.w * q4.w;
        xa += __shfl_xor(xa, 1, 64);
        xa += __shfl_xor(xa, 2, 64);
        xa += __shfl_xor(xa, 4, 64);
        xa += __shfl_xor(xa, 8, 64);
        const float mn = fmaxf(m, xa);
        const float sc = __expf(m - mn);
        const float wa = __expf(xa - mn);
        l = l * sc + wa;
        acc.x = acc.x * sc + wa * va.x;
        acc.y = acc.y * sc + wa * va.y;
        acc.z = acc.z * sc + wa * va.z;
        acc.w = acc.w * sc + wa * va.w;
        m = mn;
    }

    const size_t pidx = (size_t)(n * H_ + h) * nchunk + chunk;
    if (t == 0) { ws_m[pidx] = m; ws_l[pidx] = l; }
    *(f32x4*)(ws_acc + pidx * 64 + 4 * t) = acc;
}

// Kernel 2: block = (n,h), 256 threads = 16 (wave,g) groups x 16 lanes.
// Each (wave,g) group online-merges chunks c = wave*4+g, +16, +32, ... in a
// single pass (f32x4 partial reads). Groups combine via shfl(16,32), waves
// via LDS. Max serial dependent-load depth: ceil(nv/16) <= 8.
__global__ __launch_bounds__(256, 8)
void attn_reduce(const int* __restrict__ lens,
                 const float* __restrict__ ws_m,
                 const float* __restrict__ ws_l,
                 const float* __restrict__ ws_acc,
                 float* __restrict__ out,
                 int chunk_sz, int nchunk)
{
    const int nh = blockIdx.x;                    // n*H_ + h
    const int n  = nh >> 4;
    const int tid  = threadIdx.x;
    const int wave = tid >> 6;                    // 0..3
    const int lane = tid & 63;
    const int g    = lane >> 4;                   // chunk sub-index 0..3
    const int t    = lane & 15;                   // dim quarter: d = 4t..4t+3

    const int len = lens[n];
    const int nv  = (min(len, S_) + chunk_sz - 1) / chunk_sz;   // >= 1

    const size_t base = (size_t)nh * nchunk;

    float m = -1e30f, l = 0.f;
    f32x4 acc = (f32x4)0.f;

    #pragma unroll 2
    for (int c = wave * 4 + g; c < nv; c += 16) {
        const float mc = ws_m[base + c];          // broadcast within group
        const float lc = ws_l[base + c];
        const f32x4 ac = *(const f32x4*)(ws_acc + (base + c) * 64 + 4 * t);
        const float mn = fmaxf(m, mc);
        const float so = __expf(m - mn);
        const float sn = __expf(mc - mn);
        l = l * so + lc * sn;
        acc.x = acc.x * so + ac.x * sn;
        acc.y = acc.y * so + ac.y * sn;
        acc.z = acc.z * so + ac.z * sn;
        acc.w = acc.w * so + ac.w * sn;
        m = mn;
    }

    // combine the 4 g-groups within the wave
    float M = m;
    M = fmaxf(M, __shfl_xor(M, 16, 64));
    M = fmaxf(M, __shfl_xor(M, 32, 64));
    const float e = __expf(m - M);                // empty group: l=0, acc=0 anyway
    l *= e;
    acc.x *= e; acc.y *= e; acc.z *= e; acc.w *= e;
    l     += __shfl_xor(l, 16, 64);     l     += __shfl_xor(l, 32, 64);
    acc.x += __shfl_xor(acc.x, 16, 64); acc.x += __shfl_xor(acc.x, 32, 64);
    acc.y += __shfl_xor(acc.y, 16, 64); acc.y += __shfl_xor(acc.y, 32, 64);
    acc.z += __shfl_xor(acc.z, 16, 64); acc.z += __shfl_xor(acc.z, 32, 64);
    acc.w += __shfl_xor(acc.w, 16, 64); acc.w += __shfl_xor(acc.w, 32, 64);

    // combine the 4 waves via LDS
    __shared__ float sm[4], sl[4];
    __shared__ f32x4 sacc[4][16];
    if (lane == 0) { sm[wave] = M; sl[wave] = l; }
    if (lane < 16) sacc[wave][t] = acc;
    __syncthreads();

    if (wave == 0 && lane < 16) {
        const float Mb = fmaxf(fmaxf(sm[0], sm[1]), fmaxf(sm[2], sm[3]));
        float L = 0.f;
        f32x4 A = (f32x4)0.f;
        #pragma unroll
        for (int wv = 0; wv < 4; ++wv) {
            const float ee = __expf(sm[wv] - Mb); // empty wave contributes 0
            L += sl[wv] * ee;
            const f32x4 a = sacc[wv][t];
            A.x += a.x * ee; A.y += a.y * ee; A.z += a.z * ee; A.w += a.w * ee;
        }
        const float inv = 1.f / L;
        f32x4 O; O.x = A.x * inv; O.y = A.y * inv; O.z = A.z * inv; O.w = A.w * inv;
        *(f32x4*)(out + (size_t)nh * D_ + 4 * t) = O;
    }
}

extern "C" void kernel_launch(void* const* d_in, const int* in_sizes, int n_in,
                              void* d_out, int out_size, void* d_ws, size_t ws_size,
                              hipStream_t stream) {
    const float* q    = (const float*)d_in[0];   // [N,H,E]
    const float* k    = (const float*)d_in[1];   // [N,S,H,E]
    const float* v    = (const float*)d_in[2];   // [N,S,H,D]
    const int*   lens = (const int*)d_in[3];     // [N]
    float* out = (float*)d_out;                  // [N,H,D]

    const size_t NH = (size_t)N_ * H_;
    // pick the largest chunk count whose partials fit the workspace
    int nchunk = 8;
    if      (ws_size >= NH * 128 * 66 * sizeof(float)) nchunk = 128; // ~17.3 MB
    else if (ws_size >= NH * 64  * 66 * sizeof(float)) nchunk = 64;
    else if (ws_size >= NH * 32  * 66 * sizeof(float)) nchunk = 32;
    else if (ws_size >= NH * 16  * 66 * sizeof(float)) nchunk = 16;
    const int chunk_sz = S_ / nchunk;

    float* ws_m   = (float*)d_ws;
    float* ws_l   = ws_m + NH * nchunk;
    float* ws_acc = ws_l + NH * nchunk;

    dim3 g1(nchunk, N_);
    attn_partial<<<g1, 256, 0, stream>>>(q, k, v, lens, ws_m, ws_l, ws_acc,
                                         chunk_sz, nchunk);

    attn_reduce<<<(int)NH, 256, 0, stream>>>(lens, ws_m, ws_l, ws_acc, out,
                                             chunk_sz, nchunk);
}